// Round 11
// baseline (128.991 us; speedup 1.0000x reference)
//
#include <hip/hip_runtime.h>
#include <hip/hip_bf16.h>
#include <math.h>

// NTXent loss, N=8192 rows, D=128.
// loss = mean_i [ log(sum_{j!=i} exp(2*cos_ij)) - 2*cos_{i,partner} ]
// R19: R18 (barrier-free reg-streaming) gave the first clean counters:
// VGPR 68, no spill, Mfma/VALU both ~9%, occ 25%, 67us. Compiler discarded
// the double buffer (104 live planned -> 68 allocated; loads serialized
// before use) AND 68 VGPR is just past the 64-reg occupancy cliff -> only
// 4 waves/SIMD, so each chunk's ~300cy L2 gather latency is exposed.
// R19 embraces the single-buffer loop and drowns latency in TLP: per-wave
// state <= ~60 VGPR (chunk = 16 cols, b[4]; a[2][4]; rs[2][4]),
// launch_bounds(256,8) caps at 64 -> 8 waves/SIMD; cg = 256 cols ->
// 2048 blocks = exactly 8 blocks/CU; cg = bid&31 makes all 32 waves on a
// CU stream the SAME B-panel (L1 reuse; 256 = 0 mod 32). No LDS/barriers.

typedef __attribute__((ext_vector_type(8))) short bf16x8;   // 8 bf16 = 4 VGPRs
typedef __attribute__((ext_vector_type(4))) float f32x4;

#define NROWS 8192
#define DDIM  128
#define BHALF 4096
#define NCG   32                    // col groups
#define CGSZ  256                   // cols per group
#define NCHUNK 16                   // 16 chunks of 16 cols
// zn scaled by sqrt(2/ln2): acc = (2/ln2)*cos, exp(2cos) = exp2(acc)
#define SQRT_E2S 1.6986435980707531f
#define LN2      0.6931471805599453f
#define EXPDIAG  7.38905609893065f

static __device__ __forceinline__ unsigned short f2bf(float f) {
  unsigned int u = __float_as_uint(f);
  unsigned int r = (u + 0x7fffu + ((u >> 16) & 1u)) >> 16;   // RNE
  return (unsigned short)r;
}

// ---- Kernel 1: normalize (scaled) + fp32 pair-dots + zero out ------------
// Block b: waves 0,1 -> rows 2b,2b+1 (zi); waves 2,3 -> their partners (zj).
__global__ void norm_kernel(const float* __restrict__ zi, const float* __restrict__ zj,
                            unsigned short* __restrict__ zn,
                            float* __restrict__ pos, float* __restrict__ out) {
  __shared__ float2 xbuf[2][64];
  int wave = threadIdx.x >> 6;
  int lane = threadIdx.x & 63;
  int pi   = blockIdx.x * 2 + (wave & 1);           // pair index
  int row  = pi + (wave >> 1) * BHALF;
  const float* src = (row < BHALF) ? (zi + (size_t)row * DDIM)
                                   : (zj + (size_t)(row - BHALF) * DDIM);
  float2 v = *(const float2*)(src + 2 * lane);
  float ss = v.x * v.x + v.y * v.y;
  #pragma unroll
  for (int off = 1; off < 64; off <<= 1) ss += __shfl_xor(ss, off);
  float scale = SQRT_E2S / fmaxf(sqrtf(ss), 1e-8f);
  v.x *= scale; v.y *= scale;
  unsigned int lo = f2bf(v.x), hi = f2bf(v.y);
  ((unsigned int*)(zn + (size_t)row * DDIM))[lane] = lo | (hi << 16);

  if (wave >= 2) xbuf[wave - 2][lane] = v;
  __syncthreads();
  if (wave < 2) {                                    // d = (2/ln2)*cos(i, i+B)
    float2 w = xbuf[wave][lane];
    float d = v.x * w.x + v.y * w.y;
    #pragma unroll
    for (int off = 1; off < 64; off <<= 1) d += __shfl_xor(d, off);
    if (lane == 0) pos[pi] = d;
  }
  if (blockIdx.x == 0 && threadIdx.x == 0) out[0] = 0.0f;
}

// ---- Kernel 2: full-matrix sim + exp + row partial sums ------------------
// 2048 blocks x 4 autonomous waves (no LDS, no barriers). Wave: 32-row
// strip = (bid>>5)*4 + w; col group cg = bid&31 (256 cols, same panel for
// all waves on a CU). B streams L2/L1 -> regs, 16 cols/chunk (b[4]).
__global__ __launch_bounds__(256, 8)
void sim_kernel(const unsigned short* __restrict__ zn, float* __restrict__ part) {
  const int w    = threadIdx.x >> 6;
  const int lane = threadIdx.x & 63;
  const int l15  = lane & 15;
  const int quad = lane >> 4;

  const int cg    = blockIdx.x & 31;
  const int strip = (blockIdx.x >> 5) * 4 + w;       // 0..255
  const int row_base = strip * 32;
  const int col0     = cg * CGSZ;

  // A fragments: A[m=l15][k=quad*8+kf*32+j], 2 mi-tiles x 4 k-frags = 32 VGPR.
  bf16x8 a[2][4];
  const unsigned short* abase = zn + (size_t)(row_base + l15) * DDIM + quad * 8;
  #pragma unroll
  for (int mi = 0; mi < 2; ++mi)
    #pragma unroll
    for (int kf = 0; kf < 4; ++kf)
      a[mi][kf] = *(const bf16x8*)(abase + mi * 16 * DDIM + kf * 32);

  float rs[2][4];
  #pragma unroll
  for (int mi = 0; mi < 2; ++mi)
    #pragma unroll
    for (int r = 0; r < 4; ++r) rs[mi][r] = 0.0f;

  // B fragment base: same lane pattern as A (sim = zn * zn^T).
  const unsigned short* bbase = zn + (size_t)(col0 + l15) * DDIM + quad * 8;

  #pragma unroll 1
  for (int ch = 0; ch < NCHUNK; ++ch) {
    const unsigned short* bp = bbase + (size_t)ch * 16 * DDIM;
    bf16x8 b[4];
    #pragma unroll
    for (int kf = 0; kf < 4; ++kf)
      b[kf] = *(const bf16x8*)(bp + kf * 32);
    f32x4 z = {0.0f, 0.0f, 0.0f, 0.0f};
    f32x4 acc0 = __builtin_amdgcn_mfma_f32_16x16x32_bf16(a[0][0], b[0], z, 0, 0, 0);
    f32x4 acc1 = __builtin_amdgcn_mfma_f32_16x16x32_bf16(a[1][0], b[0], z, 0, 0, 0);
    #pragma unroll
    for (int kf = 1; kf < 4; ++kf) {
      acc0 = __builtin_amdgcn_mfma_f32_16x16x32_bf16(a[0][kf], b[kf], acc0, 0, 0, 0);
      acc1 = __builtin_amdgcn_mfma_f32_16x16x32_bf16(a[1][kf], b[kf], acc1, 0, 0, 0);
    }
    #pragma unroll
    for (int r = 0; r < 4; ++r) {
      rs[0][r] += __builtin_amdgcn_exp2f(acc0[r]);
      rs[1][r] += __builtin_amdgcn_exp2f(acc1[r]);
    }
  }

  // Row reduce across the 16 cols each l15 covers. C/D layout: col=l15,
  // row=quad*4+reg. Plain store to disjoint slot cg.
  #pragma unroll
  for (int mi = 0; mi < 2; ++mi)
    #pragma unroll
    for (int r = 0; r < 4; ++r) {
      float v = rs[mi][r];
      v += __shfl_xor(v, 1);
      v += __shfl_xor(v, 2);
      v += __shfl_xor(v, 4);
      v += __shfl_xor(v, 8);
      if (l15 == 0)
        part[(size_t)cg * NROWS + row_base + mi * 16 + quad * 4 + r] = v;
    }
}

// ---- Kernel 3: sum 32 slots per row, logs + mean -------------------------
__global__ void finalize_kernel(const float* __restrict__ part,
                                const float* __restrict__ pos,
                                float* __restrict__ out) {
  __shared__ float red[4];
  int r = blockIdx.x * 256 + threadIdx.x;            // grid 32 x 256 = 8192 rows
  float s = 0.0f;
  #pragma unroll
  for (int k = 0; k < NCG; ++k) s += part[(size_t)k * NROWS + r];
  // per row: logsumexp(logits) - logits[0] = log(S - e^2) - ln2 * pos
  float v = logf(s - EXPDIAG) - LN2 * pos[r & (BHALF - 1)];
  #pragma unroll
  for (int off = 1; off < 64; off <<= 1) v += __shfl_xor(v, off);
  int wave = threadIdx.x >> 6, lane = threadIdx.x & 63;
  if (lane == 0) red[wave] = v;
  __syncthreads();
  if (threadIdx.x == 0)
    atomicAdd(out, (red[0] + red[1] + red[2] + red[3]) * (1.0f / 8192.0f));
}

extern "C" void kernel_launch(void* const* d_in, const int* in_sizes, int n_in,
                              void* d_out, int out_size, void* d_ws, size_t ws_size,
                              hipStream_t stream) {
  const float* zi = (const float*)d_in[0];
  const float* zj = (const float*)d_in[1];
  char* ws = (char*)d_ws;
  unsigned short* zn = (unsigned short*)ws;                       // 2 MB
  float* part = (float*)(ws + (size_t)NROWS * DDIM * 2);          // 1 MB (32x8192)
  float* pos  = (float*)(ws + (size_t)NROWS * DDIM * 2
                            + (size_t)NCG * NROWS * 4);           // 16 KB
  float* out = (float*)d_out;

  norm_kernel<<<2048, 256, 0, stream>>>(zi, zj, zn, pos, out);
  sim_kernel<<<2048, 256, 0, stream>>>(zn, part);
  finalize_kernel<<<32, 256, 0, stream>>>(part, pos, out);
}

// Round 12
// 81.801 us; speedup vs baseline: 1.5769x; 1.5769x over previous
//
#include <hip/hip_runtime.h>
#include <hip/hip_bf16.h>
#include <math.h>

// NTXent loss, N=8192 rows, D=128.
// loss = mean_i [ log(sum_{j!=i} exp(2*cos_ij)) - 2*cos_{i,partner} ]
// R20: R19 was decisive: occupancy 25->82% (VGPR 32) with ZERO time change
// (67->70us) => not TLP-starved. The direct-from-global B-fragment load is
// a 64-line gather (lane=row, stride 256B): 32 waves/CU x 16 chunks x 4
// loads x 64 lines = 131K TA-cycles/CU = 55us ~= measured. R18==R19 because
// the gather count is occupancy-independent. LDS staging fixes the gather
// (coalesced glds, LDS does the scatter); R17's ~44us was instead the
// lockstep phase tax (16 tiny phases). R20 = R17 skeleton with 4x bigger
// phases: chunk=128 cols (32KB), double-buffered 64KB LDS (2 blocks/CU),
// cg=1024 cols -> 8 phases; per phase/wave 8 independent ni-chains
// (4 ds_read + 8 MFMA + 8 exp2 each) for intra-wave ILP. 512 blocks.
// Counted vmcnt: A(8)+buf0(8)+buf1(8)=24; phases 0..5 vmcnt(8)+restage,
// 6 vmcnt(8), 7 vmcnt(0). launch_bounds(256,2) (the only non-spill cap).

typedef __attribute__((ext_vector_type(8))) short bf16x8;   // 8 bf16 = 4 VGPRs
typedef __attribute__((ext_vector_type(4))) float f32x4;

#define NROWS 8192
#define DDIM  128
#define BHALF 4096
#define NCG   8                     // col groups
#define CGSZ  1024                  // cols per group
#define CHUNKC 128                  // cols per chunk (32 KB)
#define NPH   8                     // phases per block
// zn scaled by sqrt(2/ln2): acc = (2/ln2)*cos, exp(2cos) = exp2(acc)
#define SQRT_E2S 1.6986435980707531f
#define LN2      0.6931471805599453f
#define EXPDIAG  7.38905609893065f

static __device__ __forceinline__ unsigned short f2bf(float f) {
  unsigned int u = __float_as_uint(f);
  unsigned int r = (u + 0x7fffu + ((u >> 16) & 1u)) >> 16;   // RNE
  return (unsigned short)r;
}

static __device__ __forceinline__ void glds16(const unsigned short* g, unsigned short* l) {
  __builtin_amdgcn_global_load_lds((const __attribute__((address_space(1))) unsigned int*)g,
                                   (__attribute__((address_space(3))) unsigned int*)l,
                                   16, 0, 0);
}

// ---- Kernel 1: normalize (scaled) + fp32 pair-dots + zero out ------------
// Block b: waves 0,1 -> rows 2b,2b+1 (zi); waves 2,3 -> their partners (zj).
__global__ void norm_kernel(const float* __restrict__ zi, const float* __restrict__ zj,
                            unsigned short* __restrict__ zn,
                            float* __restrict__ pos, float* __restrict__ out) {
  __shared__ float2 xbuf[2][64];
  int wave = threadIdx.x >> 6;
  int lane = threadIdx.x & 63;
  int pi   = blockIdx.x * 2 + (wave & 1);           // pair index
  int row  = pi + (wave >> 1) * BHALF;
  const float* src = (row < BHALF) ? (zi + (size_t)row * DDIM)
                                   : (zj + (size_t)(row - BHALF) * DDIM);
  float2 v = *(const float2*)(src + 2 * lane);
  float ss = v.x * v.x + v.y * v.y;
  #pragma unroll
  for (int off = 1; off < 64; off <<= 1) ss += __shfl_xor(ss, off);
  float scale = SQRT_E2S / fmaxf(sqrtf(ss), 1e-8f);
  v.x *= scale; v.y *= scale;
  unsigned int lo = f2bf(v.x), hi = f2bf(v.y);
  ((unsigned int*)(zn + (size_t)row * DDIM))[lane] = lo | (hi << 16);

  if (wave >= 2) xbuf[wave - 2][lane] = v;
  __syncthreads();
  if (wave < 2) {                                    // d = (2/ln2)*cos(i, i+B)
    float2 w = xbuf[wave][lane];
    float d = v.x * w.x + v.y * w.y;
    #pragma unroll
    for (int off = 1; off < 64; off <<= 1) d += __shfl_xor(d, off);
    if (lane == 0) pos[pi] = d;
  }
  if (blockIdx.x == 0 && threadIdx.x == 0) out[0] = 0.0f;
}

// ---- Kernel 2: full-matrix sim + exp + row partial sums ------------------
// 512 blocks: strip = bid>>3 (128 rows), cg = bid&7 (1024 cols).
// B staged 128 cols/chunk into 2x32KB LDS double buffer via glds
// (coalesced; XOR-swizzled slots); 8 phases, counted vmcnt, rolled loop.
__global__ __launch_bounds__(256, 2)
void sim_kernel(const unsigned short* __restrict__ zn, float* __restrict__ part) {
  __shared__ unsigned short lds[2 * CHUNKC * DDIM];  // 64 KB

  const int w    = threadIdx.x >> 6;
  const int lane = threadIdx.x & 63;
  const int l15  = lane & 15;
  const int quad = lane >> 4;

  const int strip = blockIdx.x >> 3;
  const int cg    = blockIdx.x & 7;
  const int row_base = strip * 128 + w * 32;
  const int col0     = cg * CGSZ;

  // A fragments: A[m=l15][k=quad*8+kf*32+j], 2 mi x 4 kf = 32 VGPR.
  // Issued FIRST (oldest in vmcnt order), pinned by sched_barrier.
  bf16x8 a[2][4];
  const unsigned short* abase = zn + (size_t)(row_base + l15) * DDIM + quad * 8;
  #pragma unroll
  for (int mi = 0; mi < 2; ++mi)
    #pragma unroll
    for (int kf = 0; kf < 4; ++kf)
      a[mi][kf] = *(const bf16x8*)(abase + mi * 16 * DDIM + kf * 32);
  __builtin_amdgcn_sched_barrier(0);   // pin: A-loads strictly before glds

  // Staging: chunk = 128 zn-rows (cols of sim). Wave w stages rows
  // w*32..w*32+31 via 8 glds16 (1 KB each: 4 rows). Slot layout XOR-
  // swizzled within each 256B row: slot s holds data chunk s^(r&15).
  const int rq = lane >> 4;            // row-within-4 for staging
  const int cl = lane & 15;            // 16B slot index

#define STAGE(CH, BUF)                                                         \
  {                                                                            \
    _Pragma("unroll")                                                          \
    for (int i = 0; i < 8; ++i) {                                              \
      int r = (w * 8 + i) * 4 + rq;                                            \
      int c = cl ^ (r & 15);                                                   \
      glds16(zn + (size_t)(col0 + (CH) * CHUNKC + r) * DDIM + c * 8,           \
             lds + (BUF) * (CHUNKC * DDIM) + (w * 8 + i) * 512);               \
    }                                                                          \
  }

  STAGE(0, 0)
  STAGE(1, 1)
  __builtin_amdgcn_sched_barrier(0);   // pin: glds issued before loop body

  int rdoff[4];
  #pragma unroll
  for (int kf = 0; kf < 4; ++kf)
    rdoff[kf] = l15 * DDIM + (((quad + 4 * kf) ^ l15) << 3);

  float rs[2][4];
  #pragma unroll
  for (int mi = 0; mi < 2; ++mi)
    #pragma unroll
    for (int r = 0; r < 4; ++r) rs[mi][r] = 0.0f;

#define COMPUTE(LB)                                                            \
  {                                                                            \
    _Pragma("unroll")                                                          \
    for (int ni = 0; ni < 8; ++ni) {                                           \
      bf16x8 b[4];                                                             \
      _Pragma("unroll")                                                        \
      for (int kf = 0; kf < 4; ++kf)                                           \
        b[kf] = *(const bf16x8*)((LB) + ni * 16 * DDIM + rdoff[kf]);           \
      f32x4 z = {0.0f, 0.0f, 0.0f, 0.0f};                                      \
      f32x4 acc0 = __builtin_amdgcn_mfma_f32_16x16x32_bf16(a[0][0], b[0], z, 0, 0, 0); \
      f32x4 acc1 = __builtin_amdgcn_mfma_f32_16x16x32_bf16(a[1][0], b[0], z, 0, 0, 0); \
      _Pragma("unroll")                                                        \
      for (int kf = 1; kf < 4; ++kf) {                                         \
        acc0 = __builtin_amdgcn_mfma_f32_16x16x32_bf16(a[0][kf], b[kf], acc0, 0, 0, 0); \
        acc1 = __builtin_amdgcn_mfma_f32_16x16x32_bf16(a[1][kf], b[kf], acc1, 0, 0, 0); \
      }                                                                        \
      _Pragma("unroll")                                                        \
      for (int r = 0; r < 4; ++r) {                                            \
        rs[0][r] += __builtin_amdgcn_exp2f(acc0[r]);                           \
        rs[1][r] += __builtin_amdgcn_exp2f(acc1[r]);                           \
      }                                                                        \
    }                                                                          \
  }

  // Phases 0..5: wait chunk ch (vmcnt(8): ch+1's 8 issues remain), compute,
  // barrier, restage buf with chunk ch+2.
  #pragma unroll 1
  for (int ch = 0; ch < 6; ++ch) {
    asm volatile("s_waitcnt vmcnt(8)" ::: "memory");
    __builtin_amdgcn_s_barrier();
    __builtin_amdgcn_sched_barrier(0);
    const unsigned short* lb = lds + (ch & 1) * (CHUNKC * DDIM);
    COMPUTE(lb)
    __builtin_amdgcn_sched_barrier(0);
    __builtin_amdgcn_s_barrier();
    STAGE(ch + 2, (ch & 1))
  }
  // Phase 6: chunk 6 in buf 0 (8 of chunk 7 still in flight).
  asm volatile("s_waitcnt vmcnt(8)" ::: "memory");
  __builtin_amdgcn_s_barrier();
  __builtin_amdgcn_sched_barrier(0);
  COMPUTE(lds)
  // Phase 7: chunk 7 in buf 1, drain all.
  asm volatile("s_waitcnt vmcnt(0)" ::: "memory");
  __builtin_amdgcn_s_barrier();
  __builtin_amdgcn_sched_barrier(0);
  COMPUTE(lds + CHUNKC * DDIM)
#undef COMPUTE
#undef STAGE

  // Row reduce across the 16 cols each l15 covers. C/D layout: col=l15,
  // row=quad*4+reg. Plain store to disjoint slot cg.
  #pragma unroll
  for (int mi = 0; mi < 2; ++mi)
    #pragma unroll
    for (int r = 0; r < 4; ++r) {
      float v = rs[mi][r];
      v += __shfl_xor(v, 1);
      v += __shfl_xor(v, 2);
      v += __shfl_xor(v, 4);
      v += __shfl_xor(v, 8);
      if (l15 == 0)
        part[(size_t)cg * NROWS + row_base + mi * 16 + quad * 4 + r] = v;
    }
}

// ---- Kernel 3: sum 8 slots per row, logs + mean --------------------------
__global__ void finalize_kernel(const float* __restrict__ part,
                                const float* __restrict__ pos,
                                float* __restrict__ out) {
  __shared__ float red[4];
  int r = blockIdx.x * 256 + threadIdx.x;            // grid 32 x 256 = 8192 rows
  float s = 0.0f;
  #pragma unroll
  for (int k = 0; k < NCG; ++k) s += part[(size_t)k * NROWS + r];
  // per row: logsumexp(logits) - logits[0] = log(S - e^2) - ln2 * pos
  float v = logf(s - EXPDIAG) - LN2 * pos[r & (BHALF - 1)];
  #pragma unroll
  for (int off = 1; off < 64; off <<= 1) v += __shfl_xor(v, off);
  int wave = threadIdx.x >> 6, lane = threadIdx.x & 63;
  if (lane == 0) red[wave] = v;
  __syncthreads();
  if (threadIdx.x == 0)
    atomicAdd(out, (red[0] + red[1] + red[2] + red[3]) * (1.0f / 8192.0f));
}

extern "C" void kernel_launch(void* const* d_in, const int* in_sizes, int n_in,
                              void* d_out, int out_size, void* d_ws, size_t ws_size,
                              hipStream_t stream) {
  const float* zi = (const float*)d_in[0];
  const float* zj = (const float*)d_in[1];
  char* ws = (char*)d_ws;
  unsigned short* zn = (unsigned short*)ws;                       // 2 MB
  float* part = (float*)(ws + (size_t)NROWS * DDIM * 2);          // 256 KB (8x8192)
  float* pos  = (float*)(ws + (size_t)NROWS * DDIM * 2
                            + (size_t)NCG * NROWS * 4);           // 16 KB
  float* out = (float*)d_out;

  norm_kernel<<<2048, 256, 0, stream>>>(zi, zj, zn, pos, out);
  sim_kernel<<<512, 256, 0, stream>>>(zn, part);
  finalize_kernel<<<32, 256, 0, stream>>>(part, pos, out);
}